// Round 1
// baseline (120.843 us; speedup 1.0000x reference)
//
#include <hip/hip_runtime.h>

// FeatureTransformer: out[b,:] = bias + sum_k weight[idx[b,k],:] * val[b,k]
// B=8192, K=32, NUM_FEATURES=40960, D=1024. All f32; idx int32 (-1 = pad).

#define K_SLOTS 32
#define D_OUT 1024
#define BDIM 256   // 1024 / 4 floats per thread

__global__ __launch_bounds__(BDIM, 4) void feature_transformer_kernel(
    const int* __restrict__ feature_indices,   // [B, 32]
    const float* __restrict__ feature_values,  // [B, 32]
    const float* __restrict__ weight,          // [40960, 1024]
    const float* __restrict__ bias,            // [1024]
    float* __restrict__ out)                   // [B, 1024]
{
    const int b = blockIdx.x;
    const int t = threadIdx.x;

    __shared__ int   s_idx[K_SLOTS];
    __shared__ float s_val[K_SLOTS];
    __shared__ int   s_count;

    // Wave 0, lanes 0..31: load the 32 (idx,val) pairs and compact out the
    // padded (-1) slots with a ballot-scan. Branch-free main loop follows.
    if (t < K_SLOTS) {
        const int   fi = feature_indices[b * K_SLOTS + t];
        const float fv = feature_values[b * K_SLOTS + t];
        const bool valid = (fi >= 0);
        const unsigned long long m = __ballot(valid);          // lanes 32..63 inactive
        const int pos = __popcll(m & ((1ull << t) - 1ull));
        if (valid) {
            s_idx[pos] = fi;
            s_val[pos] = fv;
        }
        if (t == 0) s_count = __popcll(m);
    }
    __syncthreads();

    // Accumulator = bias chunk (4 floats per thread, coalesced float4).
    float4 acc = reinterpret_cast<const float4*>(bias)[t];

    const int cnt = s_count;   // block-uniform trip count
    for (int k = 0; k < cnt; ++k) {
        const int   fi = s_idx[k];     // block-uniform -> LDS broadcast
        const float fv = s_val[k];
        const float4 w = *reinterpret_cast<const float4*>(
            &weight[(size_t)fi * D_OUT + (size_t)t * 4]);
        acc.x = fmaf(w.x, fv, acc.x);
        acc.y = fmaf(w.y, fv, acc.y);
        acc.z = fmaf(w.z, fv, acc.z);
        acc.w = fmaf(w.w, fv, acc.w);
    }

    reinterpret_cast<float4*>(out)[(size_t)b * (D_OUT / 4) + t] = acc;
}

extern "C" void kernel_launch(void* const* d_in, const int* in_sizes, int n_in,
                              void* d_out, int out_size, void* d_ws, size_t ws_size,
                              hipStream_t stream) {
    const int*   feature_indices = (const int*)d_in[0];
    const float* feature_values  = (const float*)d_in[1];
    const float* weight          = (const float*)d_in[2];
    const float* bias            = (const float*)d_in[3];
    float*       out             = (float*)d_out;

    const int B = in_sizes[0] / K_SLOTS;   // 8192

    feature_transformer_kernel<<<dim3(B), dim3(BDIM), 0, stream>>>(
        feature_indices, feature_values, weight, bias, out);
}

// Round 3
// 119.600 us; speedup vs baseline: 1.0104x; 1.0104x over previous
//
#include <hip/hip_runtime.h>

// FeatureTransformer: out[b,:] = bias + sum_k weight[idx[b,k],:] * val[b,k]
// B=8192, K=32, NUM_FEATURES=40960, D=1024. All f32; idx int32 (-1 = pad).

#define K_SLOTS 32
#define D_OUT 1024
#define BDIM 256   // 1024 / 4 floats per thread

typedef float fx4 __attribute__((ext_vector_type(4)));  // clang-native vec4

__global__ __launch_bounds__(BDIM) void feature_transformer_kernel(
    const int* __restrict__ feature_indices,   // [B, 32]
    const float* __restrict__ feature_values,  // [B, 32]
    const float* __restrict__ weight,          // [40960, 1024]
    const float* __restrict__ bias,            // [1024]
    float* __restrict__ out)                   // [B, 1024]
{
    const int b = blockIdx.x;
    const int t = threadIdx.x;

    __shared__ int   s_idx[K_SLOTS];
    __shared__ float s_val[K_SLOTS];
    __shared__ int   s_count;

    // Wave 0, lanes 0..31: load the 32 (idx,val) pairs and compact out the
    // padded (-1) slots with a ballot-scan. Branch-free main loop follows.
    if (t < K_SLOTS) {
        const int   fi = feature_indices[b * K_SLOTS + t];
        const float fv = feature_values[b * K_SLOTS + t];
        const bool valid = (fi >= 0);
        const unsigned long long m = __ballot(valid);          // lanes 32..63 inactive
        const int pos = __popcll(m & ((1ull << t) - 1ull));
        if (valid) {
            s_idx[pos] = fi;
            s_val[pos] = fv;
        }
        if (t == 0) s_count = __popcll(m);
    }
    __syncthreads();

    // Accumulator = bias chunk (4 floats per thread, coalesced vec4).
    fx4 acc = *reinterpret_cast<const fx4*>(&bias[t * 4]);

    const int cnt = s_count;   // block-uniform trip count
    const size_t toff = (size_t)t * 4;

    int k = 0;
    // 4-deep unroll: 4 independent 16B gathers in flight per wave.
    for (; k + 4 <= cnt; k += 4) {
        const int i0 = s_idx[k + 0], i1 = s_idx[k + 1];
        const int i2 = s_idx[k + 2], i3 = s_idx[k + 3];
        const float v0 = s_val[k + 0], v1 = s_val[k + 1];
        const float v2 = s_val[k + 2], v3 = s_val[k + 3];
        const fx4 w0 = *reinterpret_cast<const fx4*>(&weight[(size_t)i0 * D_OUT + toff]);
        const fx4 w1 = *reinterpret_cast<const fx4*>(&weight[(size_t)i1 * D_OUT + toff]);
        const fx4 w2 = *reinterpret_cast<const fx4*>(&weight[(size_t)i2 * D_OUT + toff]);
        const fx4 w3 = *reinterpret_cast<const fx4*>(&weight[(size_t)i3 * D_OUT + toff]);
        acc += w0 * v0;
        acc += w1 * v1;
        acc += w2 * v2;
        acc += w3 * v3;
    }
    for (; k < cnt; ++k) {
        const int   fi = s_idx[k];
        const float fv = s_val[k];
        const fx4 w = *reinterpret_cast<const fx4*>(&weight[(size_t)fi * D_OUT + toff]);
        acc += w * fv;
    }

    // Output is write-once, never re-read this call: nontemporal store keeps
    // the 32 MB stream from evicting weight rows out of L3.
    __builtin_nontemporal_store(acc,
        reinterpret_cast<fx4*>(&out[(size_t)b * D_OUT + toff]));
}

extern "C" void kernel_launch(void* const* d_in, const int* in_sizes, int n_in,
                              void* d_out, int out_size, void* d_ws, size_t ws_size,
                              hipStream_t stream) {
    const int*   feature_indices = (const int*)d_in[0];
    const float* feature_values  = (const float*)d_in[1];
    const float* weight          = (const float*)d_in[2];
    const float* bias            = (const float*)d_in[3];
    float*       out             = (float*)d_out;

    const int B = in_sizes[0] / K_SLOTS;   // 8192

    feature_transformer_kernel<<<dim3(B), dim3(BDIM), 0, stream>>>(
        feature_indices, feature_values, weight, bias, out);
}

// Round 4
// 117.678 us; speedup vs baseline: 1.0269x; 1.0163x over previous
//
#include <hip/hip_runtime.h>

// FeatureTransformer: out[b,:] = bias + sum_k weight[idx[b,k],:] * val[b,k]
// B=8192, K=32, NUM_FEATURES=40960, D=1024. All f32; idx int32 (-1 = pad).
//
// D-chunk phasing: split D into 4 chunks of 256. Blocks are ordered
// chunk-major so the machine processes (approximately) all samples for
// chunk 0, then chunk 1, ... Each phase's gather working set is
// 40960 rows x 1KB = 42 MB << 256 MB L3, so each row-chunk is fetched from
// HBM once and the ~4.8x batch reuse hits L3.

#define K_SLOTS 32
#define D_OUT 1024
#define CHUNKS 4
#define CHUNK_W (D_OUT / CHUNKS)   // 256 floats = 1 KB
#define WAVES 4
#define BDIM (WAVES * 64)          // 256 threads; wave w = one (sample, chunk)

typedef float fx4 __attribute__((ext_vector_type(4)));

__global__ __launch_bounds__(BDIM) void feature_transformer_kernel(
    const int* __restrict__ feature_indices,   // [B, 32]
    const float* __restrict__ feature_values,  // [B, 32]
    const float* __restrict__ weight,          // [40960, 1024]
    const float* __restrict__ bias,            // [1024]
    float* __restrict__ out,                   // [B, 1024]
    int blocks_per_chunk)                      // B / WAVES
{
    const int bid = blockIdx.x;
    const int c   = bid / blocks_per_chunk;            // chunk phase (slow axis)
    const int bq  = bid - c * blocks_per_chunk;
    const int t    = threadIdx.x;
    const int w    = t >> 6;
    const int lane = t & 63;
    const int b    = bq * WAVES + w;                   // this wave's sample

    __shared__ int   s_idx[WAVES][K_SLOTS];
    __shared__ float s_val[WAVES][K_SLOTS];
    __shared__ int   s_cnt[WAVES];

    // Per-wave: lanes 0..31 load the 32 (idx,val) pairs and compact out the
    // padded (-1) slots with a ballot-scan.
    if (lane < K_SLOTS) {
        const int   fi = feature_indices[b * K_SLOTS + lane];
        const float fv = feature_values[b * K_SLOTS + lane];
        const bool valid = (fi >= 0);
        const unsigned long long m = __ballot(valid);  // lanes 32..63 contribute 0
        const int pos = __popcll(m & ((1ull << lane) - 1ull));
        if (valid) {
            s_idx[w][pos] = fi;
            s_val[w][pos] = fv;
        }
        if (lane == 0) s_cnt[w] = __popcll(m);
    }
    __syncthreads();

    const int col = c * CHUNK_W + lane * 4;            // this thread's 4 columns
    fx4 acc = *reinterpret_cast<const fx4*>(&bias[col]);

    const int cnt = s_cnt[w];                          // wave-uniform trip count

    int k = 0;
    // 4-deep unroll: 4 independent 16B gathers in flight per wave.
    for (; k + 4 <= cnt; k += 4) {
        const int i0 = s_idx[w][k + 0], i1 = s_idx[w][k + 1];
        const int i2 = s_idx[w][k + 2], i3 = s_idx[w][k + 3];
        const float v0 = s_val[w][k + 0], v1 = s_val[w][k + 1];
        const float v2 = s_val[w][k + 2], v3 = s_val[w][k + 3];
        const fx4 w0 = *reinterpret_cast<const fx4*>(&weight[(size_t)i0 * D_OUT + col]);
        const fx4 w1 = *reinterpret_cast<const fx4*>(&weight[(size_t)i1 * D_OUT + col]);
        const fx4 w2 = *reinterpret_cast<const fx4*>(&weight[(size_t)i2 * D_OUT + col]);
        const fx4 w3 = *reinterpret_cast<const fx4*>(&weight[(size_t)i3 * D_OUT + col]);
        acc += w0 * v0;
        acc += w1 * v1;
        acc += w2 * v2;
        acc += w3 * v3;
    }
    for (; k < cnt; ++k) {
        const int   fi = s_idx[w][k];
        const float fv = s_val[w][k];
        const fx4 wv = *reinterpret_cast<const fx4*>(&weight[(size_t)fi * D_OUT + col]);
        acc += wv * fv;
    }

    // Write-once output: nontemporal so the 32 MB stream doesn't evict
    // weight rows from L3.
    __builtin_nontemporal_store(acc,
        reinterpret_cast<fx4*>(&out[(size_t)b * D_OUT + col]));
}

extern "C" void kernel_launch(void* const* d_in, const int* in_sizes, int n_in,
                              void* d_out, int out_size, void* d_ws, size_t ws_size,
                              hipStream_t stream) {
    const int*   feature_indices = (const int*)d_in[0];
    const float* feature_values  = (const float*)d_in[1];
    const float* weight          = (const float*)d_in[2];
    const float* bias            = (const float*)d_in[3];
    float*       out             = (float*)d_out;

    const int B = in_sizes[0] / K_SLOTS;      // 8192
    const int blocks_per_chunk = B / WAVES;   // 2048
    const int nblocks = blocks_per_chunk * CHUNKS;

    feature_transformer_kernel<<<dim3(nblocks), dim3(BDIM), 0, stream>>>(
        feature_indices, feature_values, weight, bias, out, blocks_per_chunk);
}

// Round 5
// 113.721 us; speedup vs baseline: 1.0626x; 1.0348x over previous
//
#include <hip/hip_runtime.h>

// FeatureTransformer: out[b,:] = bias + sum_k weight[idx[b,k],:] * val[b,k]
// B=8192, K=32, NUM_FEATURES=40960, D=1024. All f32; idx int32 (-1 = pad).
//
// Latency-bound gather => maximize memory-level parallelism:
//  - FIXED trip count of 32 (no compaction): padded slots use row 0 with
//    val=0; row 0 stays L1-resident so pads cost ~nothing, and the fixed
//    count lets the compiler keep 8 gathers in flight per wave.
//  - 4 groups x 8-deep: 8 back-to-back float4 gathers, then 8 vec FMAs.
//  - D-chunk phasing (4 x 256 cols) retained for L2/L3 locality.

#define K_SLOTS 32
#define D_OUT 1024
#define CHUNKS 4
#define CHUNK_W (D_OUT / CHUNKS)   // 256 floats = 1 KB
#define WAVES 4
#define BDIM (WAVES * 64)          // 256 threads; wave w = one (sample, chunk)
#define GDEPTH 8                   // gathers in flight per wave

typedef float fx4 __attribute__((ext_vector_type(4)));

__global__ __launch_bounds__(BDIM) void feature_transformer_kernel(
    const int* __restrict__ feature_indices,   // [B, 32]
    const float* __restrict__ feature_values,  // [B, 32]
    const float* __restrict__ weight,          // [40960, 1024]
    const float* __restrict__ bias,            // [1024]
    float* __restrict__ out,                   // [B, 1024]
    int blocks_per_chunk)                      // B / WAVES
{
    const int bid = blockIdx.x;
    const int c   = bid / blocks_per_chunk;            // chunk phase (slow axis)
    const int bq  = bid - c * blocks_per_chunk;
    const int t    = threadIdx.x;
    const int w    = t >> 6;
    const int lane = t & 63;
    const int b    = bq * WAVES + w;                   // this wave's sample

    __shared__ int   s_idx[WAVES][K_SLOTS];
    __shared__ float s_val[WAVES][K_SLOTS];

    // Per-wave: lanes 0..31 sanitize the 32 (idx,val) pairs. Padded (-1)
    // slots become (row 0, val 0.0) -- row 0 is L1-hot, effectively free.
    if (lane < K_SLOTS) {
        const int   fi = feature_indices[b * K_SLOTS + lane];
        const float fv = feature_values[b * K_SLOTS + lane];
        const bool valid = (fi >= 0);
        s_idx[w][lane] = valid ? fi : 0;
        s_val[w][lane] = valid ? fv : 0.0f;
    }
    __syncthreads();

    const int col = c * CHUNK_W + lane * 4;            // this thread's 4 columns
    fx4 acc = *reinterpret_cast<const fx4*>(&bias[col]);

    // Fixed 32 iterations: 4 groups of 8-deep gather pipelining.
    #pragma unroll
    for (int g = 0; g < K_SLOTS / GDEPTH; ++g) {
        int   idxs[GDEPTH];
        float vals[GDEPTH];
        #pragma unroll
        for (int j = 0; j < GDEPTH; ++j) {
            idxs[j] = s_idx[w][g * GDEPTH + j];        // wave-uniform broadcast
            vals[j] = s_val[w][g * GDEPTH + j];
        }
        fx4 wv[GDEPTH];
        #pragma unroll
        for (int j = 0; j < GDEPTH; ++j) {
            wv[j] = *reinterpret_cast<const fx4*>(
                &weight[(size_t)idxs[j] * D_OUT + col]);
        }
        #pragma unroll
        for (int j = 0; j < GDEPTH; ++j) {
            acc += wv[j] * vals[j];
        }
    }

    // Write-once output: nontemporal so the 32 MB stream doesn't pollute L3.
    __builtin_nontemporal_store(acc,
        reinterpret_cast<fx4*>(&out[(size_t)b * D_OUT + col]));
}

extern "C" void kernel_launch(void* const* d_in, const int* in_sizes, int n_in,
                              void* d_out, int out_size, void* d_ws, size_t ws_size,
                              hipStream_t stream) {
    const int*   feature_indices = (const int*)d_in[0];
    const float* feature_values  = (const float*)d_in[1];
    const float* weight          = (const float*)d_in[2];
    const float* bias            = (const float*)d_in[3];
    float*       out             = (float*)d_out;

    const int B = in_sizes[0] / K_SLOTS;      // 8192
    const int blocks_per_chunk = B / WAVES;   // 2048
    const int nblocks = blocks_per_chunk * CHUNKS;

    feature_transformer_kernel<<<dim3(nblocks), dim3(BDIM), 0, stream>>>(
        feature_indices, feature_values, weight, bias, out, blocks_per_chunk);
}

// Round 6
// 112.590 us; speedup vs baseline: 1.0733x; 1.0100x over previous
//
#include <hip/hip_runtime.h>

// FeatureTransformer: out[b,:] = bias + sum_k weight[idx[b,k],:] * val[b,k]
// B=8192, K=32, NUM_FEATURES=40960, D=1024. All f32; idx int32 (-1 = pad).
//
// R6: latency-bound gather; hipcc serializes gathers (VGPR=32 proves ~1 in
// flight). Fix: inline-asm global_load_dwordx4 (opaque to compiler waitcnt
// insertion) + ping-pong register groups of 8 + counted s_waitcnt vmcnt(8)
// so each wave keeps 16 KB in flight. sched_barrier(0) after each wait per
// guide rule #18 (compiler hoists reg-only ops past asm waitcnt).

#define K_SLOTS 32
#define D_OUT 1024
#define CHUNKS 4
#define CHUNK_W (D_OUT / CHUNKS)   // 256 floats = 1 KB per wave-gather
#define WAVES 4
#define BDIM (WAVES * 64)
#define G 8                        // group depth (8 x float4 = 32 VGPR/group)

typedef float fx4 __attribute__((ext_vector_type(4)));

__global__ __launch_bounds__(BDIM) void feature_transformer_kernel(
    const int* __restrict__ feature_indices,   // [B, 32]
    const float* __restrict__ feature_values,  // [B, 32]
    const float* __restrict__ weight,          // [40960, 1024]
    const float* __restrict__ bias,            // [1024]
    float* __restrict__ out,                   // [B, 1024]
    int blocks_per_chunk)                      // B / WAVES
{
    const int bid = blockIdx.x;
    const int c   = bid / blocks_per_chunk;            // D-chunk phase
    const int bq  = bid - c * blocks_per_chunk;
    const int t    = threadIdx.x;
    const int w    = t >> 6;
    const int lane = t & 63;
    const int b    = bq * WAVES + w;                   // this wave's sample

    __shared__ int   s_idx[WAVES][K_SLOTS];
    __shared__ float s_val[WAVES][K_SLOTS];

    // Sanitize: padded (-1) slots -> (row 0, val 0). Row 0 stays L1-hot, so
    // pads cost ~nothing and the trip count is a fixed 32.
    if (lane < K_SLOTS) {
        const int   fi = feature_indices[b * K_SLOTS + lane];
        const float fv = feature_values[b * K_SLOTS + lane];
        const bool valid = (fi >= 0);
        s_idx[w][lane] = valid ? fi : 0;
        s_val[w][lane] = valid ? fv : 0.0f;
    }
    __syncthreads();

    const int col = c * CHUNK_W + lane * 4;            // this thread's 4 cols
    fx4 acc = *reinterpret_cast<const fx4*>(&bias[col]);
    // Force the bias load to be materialized (and its compiler-inserted
    // vmcnt wait placed) HERE, before our manually-counted gather stream.
    asm volatile("" : "+v"(acc));

    fx4 wa[G], wb[G];

#define ISSUE(BUF, BASE)                                                      \
    _Pragma("unroll")                                                         \
    for (int j = 0; j < G; ++j) {                                             \
        const float* p =                                                      \
            weight + (size_t)s_idx[w][(BASE) + j] * D_OUT + col;              \
        asm volatile("global_load_dwordx4 %0, %1, off"                        \
                     : "=v"(BUF[j]) : "v"(p));                                \
    }

#define CONSUME(BUF, BASE)                                                    \
    _Pragma("unroll")                                                         \
    for (int j = 0; j < G; ++j) acc += BUF[j] * s_val[w][(BASE) + j];

    // Ping-pong pipeline: 16 gathers (16 KB) outstanding in steady state.
    ISSUE(wa, 0)
    ISSUE(wb, G)
    asm volatile("s_waitcnt vmcnt(8)" ::: "memory");   // wa landed, wb flying
    __builtin_amdgcn_sched_barrier(0);
    CONSUME(wa, 0)
    ISSUE(wa, 2 * G)
    asm volatile("s_waitcnt vmcnt(8)" ::: "memory");   // wb landed
    __builtin_amdgcn_sched_barrier(0);
    CONSUME(wb, G)
    ISSUE(wb, 3 * G)
    asm volatile("s_waitcnt vmcnt(8)" ::: "memory");   // wa landed
    __builtin_amdgcn_sched_barrier(0);
    CONSUME(wa, 2 * G)
    asm volatile("s_waitcnt vmcnt(0)" ::: "memory");   // drain
    __builtin_amdgcn_sched_barrier(0);
    CONSUME(wb, 3 * G)

#undef ISSUE
#undef CONSUME

    // Write-once output: nontemporal, don't pollute L3.
    __builtin_nontemporal_store(acc,
        reinterpret_cast<fx4*>(&out[(size_t)b * D_OUT + col]));
}

extern "C" void kernel_launch(void* const* d_in, const int* in_sizes, int n_in,
                              void* d_out, int out_size, void* d_ws, size_t ws_size,
                              hipStream_t stream) {
    const int*   feature_indices = (const int*)d_in[0];
    const float* feature_values  = (const float*)d_in[1];
    const float* weight          = (const float*)d_in[2];
    const float* bias            = (const float*)d_in[3];
    float*       out             = (float*)d_out;

    const int B = in_sizes[0] / K_SLOTS;      // 8192
    const int blocks_per_chunk = B / WAVES;   // 2048
    const int nblocks = blocks_per_chunk * CHUNKS;

    feature_transformer_kernel<<<dim3(nblocks), dim3(BDIM), 0, stream>>>(
        feature_indices, feature_values, weight, bias, out, blocks_per_chunk);
}

// Round 8
// 98.199 us; speedup vs baseline: 1.2306x; 1.1465x over previous
//
#include <hip/hip_runtime.h>

// FeatureTransformer: out[b,:] = bias + sum_k weight[idx[b,k],:] * val[b,k]
// B=8192, K=32, NUM_FEATURES=40960, D=1024. f32 in/out; idx int32 (-1 = pad).
//
// R8: retry of the bytes-halving experiment (R7 had a structural bug).
// Pass 1 converts the f32 table to packed-bf16 (uint = 2 bf16) in d_ws;
// pass 2 gathers 8 bf16 cols/thread (one ux4 per row), halving both the
// L2-side gather bytes AND the wave-request count vs the f32 kernel.
// All bf16 data moves through unsigned int (no ushort aliasing, no NT loads).

#define K_SLOTS 32
#define D_OUT   1024
#define ROW_U   (D_OUT / 2)      // 512 uints per weight row (2 bf16 each)
#define WAVES   4
#define BDIM    (WAVES * 64)
#define GDEPTH  8

typedef float        fx4 __attribute__((ext_vector_type(4)));
typedef unsigned int ux2 __attribute__((ext_vector_type(2)));
typedef unsigned int ux4 __attribute__((ext_vector_type(4)));

__device__ __forceinline__ unsigned int f2bf(float f) {
    const unsigned int u = __builtin_bit_cast(unsigned int, f);
    return (u + 0x7fffu + ((u >> 16) & 1u)) >> 16;   // RNE, result in [0,0xFFFF]
}
__device__ __forceinline__ float bf_lo(unsigned int u) {   // low ushort = even col
    return __builtin_bit_cast(float, u << 16);
}
__device__ __forceinline__ float bf_hi(unsigned int u) {   // high ushort = odd col
    return __builtin_bit_cast(float, u & 0xffff0000u);
}

// ---------------- pass 1: f32 -> packed bf16 (streaming) ----------------
// Thread t: 4 floats [4t,4t+4) -> one ux2 at uint offset 2t.
__global__ __launch_bounds__(256) void convert_w_kernel(
    const float* __restrict__ w, unsigned int* __restrict__ wu, long long n)
{
    const long long i = ((long long)blockIdx.x * 256 + threadIdx.x) * 4;
    if (i >= n) return;
    const fx4 a = *reinterpret_cast<const fx4*>(w + i);
    ux2 p;
    p.x = f2bf(a.x) | (f2bf(a.y) << 16);
    p.y = f2bf(a.z) | (f2bf(a.w) << 16);
    *reinterpret_cast<ux2*>(wu + (i >> 1)) = p;
}

// ---------------- pass 2: bf16 gather-scale-sum ----------------
// 2 D-chunks of 512 cols (chunk-major grid); wave = (sample, chunk);
// each thread owns 8 cols = 4 uints = one 16B ux4 load per gathered row.
__global__ __launch_bounds__(BDIM) void gather_bf16_kernel(
    const int* __restrict__ feature_indices,
    const float* __restrict__ feature_values,
    const unsigned int* __restrict__ wu,       // [40960, 512] packed bf16
    const float* __restrict__ bias,
    float* __restrict__ out,
    int blocks_per_chunk)
{
    const int bid = blockIdx.x;
    const int c   = bid / blocks_per_chunk;            // chunk 0/1 (slow axis)
    const int bq  = bid - c * blocks_per_chunk;
    const int t    = threadIdx.x;
    const int w    = t >> 6;
    const int lane = t & 63;
    const int b    = bq * WAVES + w;

    __shared__ int   s_idx[WAVES][K_SLOTS];
    __shared__ float s_val[WAVES][K_SLOTS];

    // Sanitize: pads (-1) -> (row 0, val 0); row 0 stays L1-hot.
    if (lane < K_SLOTS) {
        const int   fi = feature_indices[b * K_SLOTS + lane];
        const float fv = feature_values[b * K_SLOTS + lane];
        const bool valid = (fi >= 0);
        s_idx[w][lane] = valid ? fi : 0;
        s_val[w][lane] = valid ? fv : 0.0f;
    }
    __syncthreads();

    const int ucol = c * (ROW_U / 2) + lane * 4;       // uint offset within row
    const int col  = ucol * 2;                         // float column in [0,1024)

    fx4 acc0 = *reinterpret_cast<const fx4*>(&bias[col]);
    fx4 acc1 = *reinterpret_cast<const fx4*>(&bias[col + 4]);

    #pragma unroll
    for (int g = 0; g < K_SLOTS / GDEPTH; ++g) {
        int   idxs[GDEPTH];
        float vals[GDEPTH];
        #pragma unroll
        for (int j = 0; j < GDEPTH; ++j) {
            idxs[j] = s_idx[w][g * GDEPTH + j];        // wave-uniform broadcast
            vals[j] = s_val[w][g * GDEPTH + j];
        }
        ux4 wv[GDEPTH];
        #pragma unroll
        for (int j = 0; j < GDEPTH; ++j)
            wv[j] = *reinterpret_cast<const ux4*>(
                &wu[(size_t)idxs[j] * ROW_U + ucol]);
        #pragma unroll
        for (int j = 0; j < GDEPTH; ++j) {
            const float v = vals[j];
            const fx4 w0 = { bf_lo(wv[j].x), bf_hi(wv[j].x),
                             bf_lo(wv[j].y), bf_hi(wv[j].y) };   // cols col+0..3
            const fx4 w1 = { bf_lo(wv[j].z), bf_hi(wv[j].z),
                             bf_lo(wv[j].w), bf_hi(wv[j].w) };   // cols col+4..7
            acc0 += w0 * v;
            acc1 += w1 * v;
        }
    }

    float* op = &out[(size_t)b * D_OUT + col];
    __builtin_nontemporal_store(acc0, reinterpret_cast<fx4*>(op));
    __builtin_nontemporal_store(acc1, reinterpret_cast<fx4*>(op + 4));
}

// ---------------- fallback: f32 gather (R5-proven; if ws too small) ----------
__global__ __launch_bounds__(BDIM) void gather_f32_kernel(
    const int* __restrict__ feature_indices,
    const float* __restrict__ feature_values,
    const float* __restrict__ weight,
    const float* __restrict__ bias,
    float* __restrict__ out,
    int blocks_per_chunk)
{
    const int bid = blockIdx.x;
    const int c   = bid / blocks_per_chunk;
    const int bq  = bid - c * blocks_per_chunk;
    const int t    = threadIdx.x;
    const int w    = t >> 6;
    const int lane = t & 63;
    const int b    = bq * WAVES + w;

    __shared__ int   s_idx[WAVES][K_SLOTS];
    __shared__ float s_val[WAVES][K_SLOTS];

    if (lane < K_SLOTS) {
        const int   fi = feature_indices[b * K_SLOTS + lane];
        const float fv = feature_values[b * K_SLOTS + lane];
        const bool valid = (fi >= 0);
        s_idx[w][lane] = valid ? fi : 0;
        s_val[w][lane] = valid ? fv : 0.0f;
    }
    __syncthreads();

    const int col = c * 256 + lane * 4;
    fx4 acc = *reinterpret_cast<const fx4*>(&bias[col]);

    #pragma unroll
    for (int g = 0; g < K_SLOTS / GDEPTH; ++g) {
        int   idxs[GDEPTH];
        float vals[GDEPTH];
        #pragma unroll
        for (int j = 0; j < GDEPTH; ++j) {
            idxs[j] = s_idx[w][g * GDEPTH + j];
            vals[j] = s_val[w][g * GDEPTH + j];
        }
        fx4 wv[GDEPTH];
        #pragma unroll
        for (int j = 0; j < GDEPTH; ++j)
            wv[j] = *reinterpret_cast<const fx4*>(
                &weight[(size_t)idxs[j] * D_OUT + col]);
        #pragma unroll
        for (int j = 0; j < GDEPTH; ++j) acc += wv[j] * vals[j];
    }

    __builtin_nontemporal_store(acc,
        reinterpret_cast<fx4*>(&out[(size_t)b * D_OUT + col]));
}

extern "C" void kernel_launch(void* const* d_in, const int* in_sizes, int n_in,
                              void* d_out, int out_size, void* d_ws, size_t ws_size,
                              hipStream_t stream) {
    const int*   feature_indices = (const int*)d_in[0];
    const float* feature_values  = (const float*)d_in[1];
    const float* weight          = (const float*)d_in[2];
    const float* bias            = (const float*)d_in[3];
    float*       out             = (float*)d_out;

    const int B = in_sizes[0] / K_SLOTS;               // 8192
    const long long wN = (long long)in_sizes[2];       // 40960*1024
    const int blocks_per_chunk = B / WAVES;            // 2048

    if (ws_size >= (size_t)wN * 2) {
        unsigned int* wu = (unsigned int*)d_ws;
        const int cblocks = (int)((wN / 4 + 255) / 256);   // 40960
        convert_w_kernel<<<dim3(cblocks), dim3(256), 0, stream>>>(weight, wu, wN);

        gather_bf16_kernel<<<dim3(blocks_per_chunk * 2), dim3(BDIM), 0, stream>>>(
            feature_indices, feature_values, wu, bias, out, blocks_per_chunk);
    } else {
        gather_f32_kernel<<<dim3(blocks_per_chunk * 4), dim3(BDIM), 0, stream>>>(
            feature_indices, feature_values, weight, bias, out, blocks_per_chunk);
    }
}